// Round 4
// baseline (48.593 us; speedup 1.0000x reference)
//
#include <hip/hip_runtime.h>

#define NK 50
#define D  256
#define NW 8          // waves per block (512 threads)
#define RPW 7         // ceil(NK/NW) rows per wave, register-resident
#define GRIDSZ 512    // persistent: 2 blocks/CU x 256 CU; 8 samples/block at bs=4096

// ---- load sample S into private regs (FRAG[RPW], C4, CNT) ----
#define LOAD_SAMPLE(FRAG, C4, CNT, S)                                          \
    {                                                                          \
        const float* irow_ = interest + (size_t)(S) * (NK * D);                \
        _Pragma("unroll")                                                      \
        for (int i_ = 0; i_ < RPW; ++i_) {                                     \
            const int k_ = wave + i_ * NW;                                     \
            if (k_ < NK)                                                       \
                FRAG[i_] = *reinterpret_cast<const float4*>(                   \
                    irow_ + (size_t)k_ * D + lane * 4);                        \
        }                                                                      \
        C4  = *reinterpret_cast<const float4*>(cand + (size_t)(S) * D + lane * 4); \
        CNT = counts[S];                                                       \
    }

// ---- full per-sample body; prefetches sample SN into (FRAGN,C4N,CNTN) first ----
#define BODY(FRAG, C4, CNT, P, S, SN, FRAGN, C4N, CNTN)                        \
    {                                                                          \
        if ((SN) < bs) LOAD_SAMPLE(FRAGN, C4N, CNTN, SN)                       \
        /* dots + wave reduce -> s_attn[P] */                                  \
        _Pragma("unroll")                                                      \
        for (int i_ = 0; i_ < RPW; ++i_) {                                     \
            const int k_ = wave + i_ * NW;                                     \
            if (k_ < NK) {                                                     \
                const float4 a4 = FRAG[i_];                                    \
                float p_ = a4.x*C4.x + a4.y*C4.y + a4.z*C4.z + a4.w*C4.w;      \
                _Pragma("unroll")                                              \
                for (int off_ = 32; off_ >= 1; off_ >>= 1)                     \
                    p_ += __shfl_xor(p_, off_, 64);                            \
                if (lane == 0) s_attn[P][k_] = p_;                             \
            }                                                                  \
        }                                                                      \
        __syncthreads();                                                       \
        int cnt_ = CNT; if (cnt_ < 1) cnt_ = 1;                                \
        int dynK_ = (int)ceilf(log2f(5.0f * (float)cnt_));                     \
        if (dynK_ < 1)  dynK_ = 1;                                             \
        if (dynK_ > NK) dynK_ = NK;                                            \
        const float my_ = (lane < NK) ? s_attn[P][lane] : 0.0f;                \
        int rank_ = 0;                                                         \
        _Pragma("unroll")                                                      \
        for (int j_ = 0; j_ < NK; ++j_) {                                      \
            const float vj_ = s_attn[P][j_];                                   \
            rank_ += (vj_ > my_) || (vj_ == my_ && j_ < lane);                 \
        }                                                                      \
        const float wsel_ = (lane < NK && rank_ < dynK_) ? my_ : 0.0f;         \
        float4 acc_ = {0.f, 0.f, 0.f, 0.f};                                    \
        _Pragma("unroll")                                                      \
        for (int i_ = 0; i_ < RPW; ++i_) {                                     \
            const int k_ = wave + i_ * NW;                                     \
            if (k_ < NK) {                                                     \
                const float w_ = __shfl(wsel_, k_, 64);                        \
                acc_.x += w_ * FRAG[i_].x;  acc_.y += w_ * FRAG[i_].y;         \
                acc_.z += w_ * FRAG[i_].z;  acc_.w += w_ * FRAG[i_].w;         \
            }                                                                  \
        }                                                                      \
        *reinterpret_cast<float4*>(&s_part[P][wave][lane * 4]) = acc_;         \
        __syncthreads();                                                       \
        if (tid < D) {                                                         \
            float r_ = 0.f;                                                    \
            _Pragma("unroll")                                                  \
            for (int w_ = 0; w_ < NW; ++w_) r_ += s_part[P][w_][tid];          \
            out[(size_t)(S) * D + tid] = r_;                                   \
        }                                                                      \
    }

__global__ __launch_bounds__(512, 4) void ica_kernel(
    const float* __restrict__ interest,   // [bs, 50, 256]
    const float* __restrict__ cand,       // [bs, 256]
    const int*   __restrict__ counts,     // [bs]
    float*       __restrict__ out,        // [bs, 256]
    int bs)
{
    const int tid  = threadIdx.x;
    const int lane = tid & 63;
    const int wave = tid >> 6;
    const int stride = gridDim.x;

    __shared__ float s_attn[2][NK];
    __shared__ float s_part[2][NW][D];

    float4 fragA[RPW], fragB[RPW];
    float4 c4A, c4B;
    int    cntA, cntB;

    int s = blockIdx.x;
    if (s >= bs) return;

    LOAD_SAMPLE(fragA, c4A, cntA, s)

    #pragma unroll 1
    for (;;) {
        const int sB = s + stride;
        BODY(fragA, c4A, cntA, 0, s, sB, fragB, c4B, cntB)
        if (sB >= bs) break;
        const int sA = sB + stride;
        BODY(fragB, c4B, cntB, 1, sB, sA, fragA, c4A, cntA)
        if (sA >= bs) break;
        s = sA;
    }
}

extern "C" void kernel_launch(void* const* d_in, const int* in_sizes, int n_in,
                              void* d_out, int out_size, void* d_ws, size_t ws_size,
                              hipStream_t stream) {
    const float* interest = (const float*)d_in[0];   // [bs,50,256]
    const float* cand     = (const float*)d_in[1];   // [bs,256]
    const int*   counts   = (const int*)d_in[2];     // [bs]
    float*       out      = (float*)d_out;           // [bs,256]

    const int bs   = in_sizes[2];                    // 4096
    const int grid = (bs < GRIDSZ) ? bs : GRIDSZ;
    ica_kernel<<<grid, 512, 0, stream>>>(interest, cand, counts, out, bs);
}

// Round 5
// 47.543 us; speedup vs baseline: 1.0221x; 1.0221x over previous
//
#include <hip/hip_runtime.h>

#define NK 50
#define D  256
#define NW 8          // waves per block (512 threads)
#define RPW 7         // k = wave + 8*i ; i=6 only for waves 0,1
#define LDSROWS 42    // B rows [0,42) prefetched via global_load_lds

typedef const __attribute__((address_space(1))) void* as1cv;
typedef __attribute__((address_space(3))) void*       as3v;

__device__ __forceinline__ void glds16(const float* g, float* s) {
    // one wave-instruction: 64 lanes x 16B -> LDS row base + lane*16 (linear)
    __builtin_amdgcn_global_load_lds((as1cv)g, (as3v)s, 16, 0, 0);
}

// raw barriers: do NOT drain vmcnt (keeps the B-prefetch in flight)
#define BAR_LGKM() asm volatile("s_waitcnt lgkmcnt(0)\n\ts_barrier" ::: "memory")
#define BAR_ALL()  asm volatile("s_waitcnt vmcnt(0) lgkmcnt(0)\n\ts_barrier" ::: "memory")

__global__ __launch_bounds__(512) void ica_kernel(
    const float* __restrict__ interest,   // [bs, 50, 256]
    const float* __restrict__ cand,       // [bs, 256]
    const int*   __restrict__ counts,     // [bs]
    float*       __restrict__ out,        // [bs, 256]
    int bs)
{
    const int tid  = threadIdx.x;
    const int lane = tid & 63;
    const int wave = tid >> 6;

    int sA = blockIdx.x * 2;
    int sB = sA + 1;
    if (sA >= bs) sA = bs - 1;   // bs even in practice; guards keep barriers uniform
    if (sB >= bs) sB = bs - 1;

    __shared__ float s_attn[NK];
    __shared__ float s_w[NK];
    __shared__ float s_part[NW][D];
    __shared__ float s_bufB[LDSROWS * D];   // 43008 B

    const float* irowA = interest + (size_t)sA * NK * D;
    const float* irowB = interest + (size_t)sB * NK * D;

    // ---- issue A loads (registers) ----
    const float4 c4A = *reinterpret_cast<const float4*>(cand + (size_t)sA * D + lane * 4);
    float4 fragA[RPW];
    #pragma unroll
    for (int i = 0; i < RPW; ++i) {
        const int k = wave + i * NW;
        if (k < NK)
            fragA[i] = *reinterpret_cast<const float4*>(irowA + (size_t)k * D + lane * 4);
    }

    // ---- issue B prefetch into LDS (fire-and-forget; rows 0..41) ----
    #pragma unroll
    for (int i = 0; i < 6; ++i) {
        const int r = wave + i * NW;
        if (r < LDSROWS)
            glds16(irowB + (size_t)r * D + lane * 4, &s_bufB[r * D]);
    }
    const float4 c4B = *reinterpret_cast<const float4*>(cand + (size_t)sB * D + lane * 4);
    const int cntA = counts[sA];
    const int cntB = counts[sB];

    // ================= sample A =================
    #pragma unroll
    for (int i = 0; i < RPW; ++i) {
        const int k = wave + i * NW;
        if (k < NK) {
            const float4 a4 = fragA[i];
            float p = a4.x*c4A.x + a4.y*c4A.y + a4.z*c4A.z + a4.w*c4A.w;
            #pragma unroll
            for (int off = 32; off >= 1; off >>= 1) p += __shfl_xor(p, off, 64);
            if (lane == 0) s_attn[k] = p;
        }
    }
    BAR_LGKM();                                   // publish s_attn (no vmcnt drain!)

    if (wave == 0) {                              // rank + weights (measured-best variant)
        int cnt = cntA < 1 ? 1 : cntA;
        int dynK = (int)ceilf(log2f(5.0f * (float)cnt));
        dynK = dynK < 1 ? 1 : (dynK > NK ? NK : dynK);
        if (lane < NK) {
            const float my = s_attn[lane];
            int rank = 0;
            #pragma unroll 1
            for (int j = 0; j < NK; ++j) {
                const float vj = s_attn[j];
                rank += (vj > my) || (vj == my && j < lane);
            }
            s_w[lane] = (rank < dynK) ? my : 0.0f;
        }
    }
    BAR_LGKM();                                   // publish s_w

    {   // phase 3: register-resident weighted sum
        float4 acc = {0.f, 0.f, 0.f, 0.f};
        #pragma unroll
        for (int i = 0; i < RPW; ++i) {
            const int k = wave + i * NW;
            if (k < NK) {
                const float w = s_w[k];
                acc.x += w * fragA[i].x;  acc.y += w * fragA[i].y;
                acc.z += w * fragA[i].z;  acc.w += w * fragA[i].w;
            }
        }
        *reinterpret_cast<float4*>(&s_part[wave][lane * 4]) = acc;
    }
    // late B rows (one per wave): rows 42..49, issued under the glds stream
    const int   lateK = (wave < 2) ? (48 + wave) : (40 + wave);
    const float4 lateB = *reinterpret_cast<const float4*>(irowB + (size_t)lateK * D + lane * 4);
    BAR_LGKM();                                   // publish s_part

    if (tid < D) {                                // store A
        float r = 0.f;
        #pragma unroll
        for (int w = 0; w < NW; ++w) r += s_part[w][tid];
        out[(size_t)sA * D + tid] = r;
    }

    BAR_ALL();   // the ONLY vmcnt(0): B prefetch + lateB landed; LDS visible to all waves

    // ================= sample B =================
    float4 fragB[RPW];
    #pragma unroll
    for (int i = 0; i < RPW; ++i) {
        const int k = wave + i * NW;
        if (k < NK) {
            if (k < LDSROWS)   // wave-uniform predicate
                fragB[i] = *reinterpret_cast<const float4*>(&s_bufB[k * D + lane * 4]);
            else
                fragB[i] = lateB;
        }
    }
    #pragma unroll
    for (int i = 0; i < RPW; ++i) {
        const int k = wave + i * NW;
        if (k < NK) {
            const float4 a4 = fragB[i];
            float p = a4.x*c4B.x + a4.y*c4B.y + a4.z*c4B.z + a4.w*c4B.w;
            #pragma unroll
            for (int off = 32; off >= 1; off >>= 1) p += __shfl_xor(p, off, 64);
            if (lane == 0) s_attn[k] = p;
        }
    }
    BAR_LGKM();

    if (wave == 0) {
        int cnt = cntB < 1 ? 1 : cntB;
        int dynK = (int)ceilf(log2f(5.0f * (float)cnt));
        dynK = dynK < 1 ? 1 : (dynK > NK ? NK : dynK);
        if (lane < NK) {
            const float my = s_attn[lane];
            int rank = 0;
            #pragma unroll 1
            for (int j = 0; j < NK; ++j) {
                const float vj = s_attn[j];
                rank += (vj > my) || (vj == my && j < lane);
            }
            s_w[lane] = (rank < dynK) ? my : 0.0f;
        }
    }
    BAR_LGKM();

    {
        float4 acc = {0.f, 0.f, 0.f, 0.f};
        #pragma unroll
        for (int i = 0; i < RPW; ++i) {
            const int k = wave + i * NW;
            if (k < NK) {
                const float w = s_w[k];
                acc.x += w * fragB[i].x;  acc.y += w * fragB[i].y;
                acc.z += w * fragB[i].z;  acc.w += w * fragB[i].w;
            }
        }
        *reinterpret_cast<float4*>(&s_part[wave][lane * 4]) = acc;
    }
    BAR_LGKM();

    if (tid < D) {
        float r = 0.f;
        #pragma unroll
        for (int w = 0; w < NW; ++w) r += s_part[w][tid];
        out[(size_t)sB * D + tid] = r;
    }
}

extern "C" void kernel_launch(void* const* d_in, const int* in_sizes, int n_in,
                              void* d_out, int out_size, void* d_ws, size_t ws_size,
                              hipStream_t stream) {
    const float* interest = (const float*)d_in[0];   // [bs,50,256]
    const float* cand     = (const float*)d_in[1];   // [bs,256]
    const int*   counts   = (const int*)d_in[2];     // [bs]
    float*       out      = (float*)d_out;           // [bs,256]

    const int bs   = in_sizes[2];                    // 4096
    const int grid = (bs + 1) / 2;                   // 2 samples per block
    ica_kernel<<<grid, 512, 0, stream>>>(interest, cand, counts, out, bs);
}

// Round 6
// 47.067 us; speedup vs baseline: 1.0324x; 1.0101x over previous
//
#include <hip/hip_runtime.h>

#define NK 50
#define D  256
#define NW 8          // waves per block (512 threads)
#define RPW 7         // k = wave + 8*i
#define GRIDSZ 512    // persistent: 8 samples/block at bs=4096

// raw barrier: waits LDS/shuffle ops only — global prefetch stays in flight
#define BAR_LGKM() asm volatile("s_waitcnt lgkmcnt(0)\n\ts_barrier" ::: "memory")

// issue sample S's loads into registers (FRAG[RPW], C4, CNT)
#define ISSUE(FRAG, C4, CNT, S)                                                \
    {                                                                          \
        const float* irow_ = interest + (size_t)(S) * (NK * D);                \
        _Pragma("unroll")                                                      \
        for (int i_ = 0; i_ < RPW; ++i_) {                                     \
            const int k_ = wave + i_ * NW;                                     \
            if (k_ < NK)                                                       \
                FRAG[i_] = *reinterpret_cast<const float4*>(                   \
                    irow_ + (size_t)k_ * D + lane * 4);                        \
        }                                                                      \
        C4  = *reinterpret_cast<const float4*>(cand + (size_t)(S) * D + lane * 4); \
        CNT = counts[S];                                                       \
    }

// per-sample body; prefetches sample SN into the OTHER buffer right after dots
#define BODY(FRAG, C4, CNT, S, FRAGN, C4N, CNTN, SN)                           \
    {                                                                          \
        /* 1. dots + wave reduce -> s_attn (consumes FRAG loads) */            \
        _Pragma("unroll")                                                      \
        for (int i_ = 0; i_ < RPW; ++i_) {                                     \
            const int k_ = wave + i_ * NW;                                     \
            if (k_ < NK) {                                                     \
                const float4 a4 = FRAG[i_];                                    \
                float p_ = a4.x*C4.x + a4.y*C4.y + a4.z*C4.z + a4.w*C4.w;      \
                _Pragma("unroll")                                              \
                for (int off_ = 32; off_ >= 1; off_ >>= 1)                     \
                    p_ += __shfl_xor(p_, off_, 64);                            \
                if (lane == 0) s_attn[k_] = p_;                                \
            }                                                                  \
        }                                                                      \
        /* 2. prefetch next sample NOW (queue was just drained by dots) */     \
        ISSUE(FRAGN, C4N, CNTN, SN)                                            \
        BAR_LGKM();                      /* publish s_attn; prefetch flies */  \
        /* 3. rank + weights (wave 0 — measured-best variant) */               \
        if (wave == 0) {                                                       \
            int cnt_ = CNT; if (cnt_ < 1) cnt_ = 1;                            \
            int dynK_ = (int)ceilf(log2f(5.0f * (float)cnt_));                 \
            if (dynK_ < 1)  dynK_ = 1;                                         \
            if (dynK_ > NK) dynK_ = NK;                                        \
            if (lane < NK) {                                                   \
                const float my_ = s_attn[lane];                                \
                int rank_ = 0;                                                 \
                _Pragma("unroll 1")                                            \
                for (int j_ = 0; j_ < NK; ++j_) {                              \
                    const float vj_ = s_attn[j_];                              \
                    rank_ += (vj_ > my_) || (vj_ == my_ && j_ < lane);         \
                }                                                              \
                s_w[lane] = (rank_ < dynK_) ? my_ : 0.0f;                      \
            }                                                                  \
        }                                                                      \
        BAR_LGKM();                      /* publish s_w */                     \
        /* 4. register-resident weighted sum (last use of FRAG) */             \
        {                                                                      \
            float4 acc_ = {0.f, 0.f, 0.f, 0.f};                                \
            _Pragma("unroll")                                                  \
            for (int i_ = 0; i_ < RPW; ++i_) {                                 \
                const int k_ = wave + i_ * NW;                                 \
                if (k_ < NK) {                                                 \
                    const float w_ = s_w[k_];                                  \
                    acc_.x += w_ * FRAG[i_].x;  acc_.y += w_ * FRAG[i_].y;     \
                    acc_.z += w_ * FRAG[i_].z;  acc_.w += w_ * FRAG[i_].w;     \
                }                                                              \
            }                                                                  \
            *reinterpret_cast<float4*>(&s_part[wave][lane * 4]) = acc_;        \
        }                                                                      \
        BAR_LGKM();                      /* publish s_part */                  \
        /* 5. cross-wave reduce + coalesced store */                           \
        if (tid < D) {                                                         \
            float r_ = 0.f;                                                    \
            _Pragma("unroll")                                                  \
            for (int w_ = 0; w_ < NW; ++w_) r_ += s_part[w_][tid];             \
            out[(size_t)(S) * D + tid] = r_;                                   \
        }                                                                      \
    }

__global__ __launch_bounds__(512, 4) void ica_kernel(
    const float* __restrict__ interest,   // [bs, 50, 256]
    const float* __restrict__ cand,       // [bs, 256]
    const int*   __restrict__ counts,     // [bs]
    float*       __restrict__ out,        // [bs, 256]
    int bs)
{
    const int tid  = threadIdx.x;
    const int lane = tid & 63;
    const int wave = tid >> 6;
    const int stride = gridDim.x;

    __shared__ float s_attn[NK];
    __shared__ float s_w[NK];
    __shared__ float s_part[NW][D];

    float4 fragA[RPW], fragB[RPW];
    float4 c4A, c4B;
    int    cntA, cntB;

    int s = blockIdx.x;                   // grid ≤ bs, so s < bs
    ISSUE(fragA, c4A, cntA, s)

    #pragma unroll 1
    for (;;) {
        const int sB  = s + stride;
        const int sBc = (sB < bs) ? sB : 0;         // clamped prefetch target
        BODY(fragA, c4A, cntA, s, fragB, c4B, cntB, sBc)
        if (sB >= bs) break;
        const int sA  = sB + stride;
        const int sAc = (sA < bs) ? sA : 0;
        BODY(fragB, c4B, cntB, sB, fragA, c4A, cntA, sAc)
        if (sA >= bs) break;
        s = sA;
    }
}

extern "C" void kernel_launch(void* const* d_in, const int* in_sizes, int n_in,
                              void* d_out, int out_size, void* d_ws, size_t ws_size,
                              hipStream_t stream) {
    const float* interest = (const float*)d_in[0];   // [bs,50,256]
    const float* cand     = (const float*)d_in[1];   // [bs,256]
    const int*   counts   = (const int*)d_in[2];     // [bs]
    float*       out      = (float*)d_out;           // [bs,256]

    const int bs   = in_sizes[2];                    // 4096
    const int grid = (bs < GRIDSZ) ? bs : GRIDSZ;
    ica_kernel<<<grid, 512, 0, stream>>>(interest, cand, counts, out, bs);
}

// Round 8
// 38.829 us; speedup vs baseline: 1.2515x; 1.2122x over previous
//
#include <hip/hip_runtime.h>

#define NK 50
#define D  256
#define NW 8          // waves per block (512 threads)
#define RPW 7         // ceil(NK/NW) rows per wave, register-resident

typedef float f4 __attribute__((ext_vector_type(4)));   // native vector: ok for nontemporal builtins

__global__ __launch_bounds__(512, 8) void ica_kernel(
    const float* __restrict__ interest,   // [bs, 50, 256]
    const float* __restrict__ cand,       // [bs, 256]
    const int*   __restrict__ counts,     // [bs]
    float*       __restrict__ out,        // [bs, 256]
    int bs)
{
    const int b    = blockIdx.x;
    const int tid  = threadIdx.x;
    const int lane = tid & 63;
    const int wave = tid >> 6;

    __shared__ float s_attn[NK];
    __shared__ float s_w[NK];
    __shared__ float s_part[NW][D];

    const float* irow = interest + (size_t)b * NK * D;

    // candidate fragment for this lane (d = lane*4 .. lane*4+3), read-once -> nontemporal
    const f4 c4 = __builtin_nontemporal_load(
        reinterpret_cast<const f4*>(cand + (size_t)b * D + lane * 4));

    // ---- phase 1a: issue ALL row loads first (ILP), fragments stay in registers ----
    f4 frag[RPW];
    #pragma unroll
    for (int i = 0; i < RPW; ++i) {
        const int k = wave + i * NW;           // wave-uniform guard
        if (k < NK)
            frag[i] = __builtin_nontemporal_load(
                reinterpret_cast<const f4*>(irow + (size_t)k * D + lane * 4));
    }

    // ---- phase 1b: dot + wave reduce -> s_attn[k] ----
    #pragma unroll
    for (int i = 0; i < RPW; ++i) {
        const int k = wave + i * NW;
        if (k < NK) {
            const f4 a4 = frag[i];
            float p = a4.x * c4.x + a4.y * c4.y + a4.z * c4.z + a4.w * c4.w;
            #pragma unroll
            for (int off = 32; off >= 1; off >>= 1)
                p += __shfl_xor(p, off, 64);
            if (lane == 0) s_attn[k] = p;
        }
    }
    __syncthreads();

    // ---- phase 2: dyn_K + exact top-k (stable argsort tie semantics) -> weights ----
    if (wave == 0) {
        int cnt = counts[b];
        if (cnt < 1) cnt = 1;
        int dynK = (int)ceilf(log2f(5.0f * (float)cnt));
        if (dynK < 1)  dynK = 1;
        if (dynK > NK) dynK = NK;

        if (lane < NK) {
            const float my = s_attn[lane];
            int rank = 0;
            #pragma unroll 1
            for (int j = 0; j < NK; ++j) {
                const float vj = s_attn[j];
                rank += (vj > my) || (vj == my && j < lane);
            }
            s_w[lane] = (rank < dynK) ? my : 0.0f;
        }
    }
    __syncthreads();

    // ---- phase 3: register-resident weighted sum (no global re-read) ----
    f4 acc = {0.f, 0.f, 0.f, 0.f};
    #pragma unroll
    for (int i = 0; i < RPW; ++i) {
        const int k = wave + i * NW;
        if (k < NK) {
            const float w = s_w[k];
            acc.x += w * frag[i].x;
            acc.y += w * frag[i].y;
            acc.z += w * frag[i].z;
            acc.w += w * frag[i].w;
        }
    }
    *reinterpret_cast<f4*>(&s_part[wave][lane * 4]) = acc;   // stride-1, conflict-free
    __syncthreads();

    // ---- phase 4: cross-wave reduce + coalesced store ----
    if (tid < D) {
        float r = 0.f;
        #pragma unroll
        for (int w = 0; w < NW; ++w)
            r += s_part[w][tid];                              // stride-1, conflict-free
        out[(size_t)b * D + tid] = r;
    }
}

extern "C" void kernel_launch(void* const* d_in, const int* in_sizes, int n_in,
                              void* d_out, int out_size, void* d_ws, size_t ws_size,
                              hipStream_t stream) {
    const float* interest = (const float*)d_in[0];   // [bs,50,256]
    const float* cand     = (const float*)d_in[1];   // [bs,256]
    const int*   counts   = (const int*)d_in[2];     // [bs]
    float*       out      = (float*)d_out;           // [bs,256]

    const int bs = in_sizes[2];                      // 4096
    ica_kernel<<<bs, 512, 0, stream>>>(interest, cand, counts, out, bs);
}